// Round 4
// baseline (231.220 us; speedup 1.0000x reference)
//
#include <hip/hip_runtime.h>

// SelfTensorProductS2Grid via bf16 MFMA (16x16x32):
//   grid[g,c] = sum_i Wt[g,i] X[i,c];  out[i,c] = sum_g Wf[g,i] grid[g,c]^2
// g is an internal contraction index -> relabeled so stage-1's C/D layout
// IS stage-2's B-operand layout (permutation baked into WfF prep).
//
// v6: occupancy/ILP attack. v5's null (LDS-W + prefetch = no change) proved
// W latency is NOT the bottleneck; wave lifetime ~61k cyc vs ~7k cyc of pipe
// work says the kernel is dependent-chain latency-bound at 3 waves/SIMD
// (144 unified regs/wave forbids a 4th). Fix: c-quarter tasks (acc 64->32
// AGPR, Bx 32->16) -> ~95 unified regs -> 5 waves/SIMD, and shorter per-kc2
// chains (2 t's). No LDS (would cap blocks/CU at 3). W read straight from
// L1/L2 (v2 style). Accepted cost: 2x W-L2 traffic - if this round is flat,
// the limiter is W bandwidth, not latency.

#define NN    4096
#define L2D   49
#define CCH   128
#define GTOT  324
#define MT1P  22              // stage-1 g-tiles of 16 (21 real + 1 zero pad)
#define KC2   11              // stage-2 g-chunks of 32

typedef __attribute__((ext_vector_type(8))) short bf16x8;
typedef __attribute__((ext_vector_type(4))) float f32x4;

#define WT_SHORTS (MT1P * 2 * 64 * 8)   // 22528
#define WF_SHORTS (4 * KC2 * 64 * 8)    // 22528

__device__ __forceinline__ short f2bf(float f) {
    union { float f; unsigned u; } x; x.f = f;
    return (short)((x.u + 0x7fffu + ((x.u >> 16) & 1u)) >> 16);   // RNE
}

// pack two f32 -> two bf16 (RNE) in one VALU op
__device__ __forceinline__ unsigned cvtpk(float lo, float hi) {
    unsigned r;
    asm("v_cvt_pk_bf16_f32 %0, %1, %2" : "=v"(r) : "v"(lo), "v"(hi));
    return r;
}

// WtF[mt][kcx][lane][j]: A[m=g=mt*16+(lane&15)][k=i=kcx*32+(lane>>4)*8+j]
// WfF[it][kc2][lane][j]: A[m=i=it*16+(lane&15)][k=glog], where
//   gphys(glog) = kc2*32 + (j>>2)*16 + (lane>>4)*4 + (j&3)   <-- the relabel
__global__ void prep_w_kernel(const float* __restrict__ Wt,
                              const float* __restrict__ Wf,
                              short* __restrict__ WtF,
                              short* __restrict__ WfF)
{
    int idx = blockIdx.x * 256 + threadIdx.x;
    if (idx < WT_SHORTS) {
        int j = idx & 7, lane = (idx >> 3) & 63, kcx = (idx >> 9) & 1, mt = idx >> 10;
        int g = mt * 16 + (lane & 15);
        int i = kcx * 32 + (lane >> 4) * 8 + j;
        WtF[idx] = f2bf((g < GTOT && i < L2D) ? Wt[g * L2D + i] : 0.0f);
    } else if (idx < WT_SHORTS + WF_SHORTS) {
        int e = idx - WT_SHORTS;
        int j = e & 7, lane = (e >> 3) & 63, t = e >> 9;
        int kc2 = t % KC2, it = t / KC2;
        int i = it * 16 + (lane & 15);
        int g = kc2 * 32 + (j >> 2) * 16 + (lane >> 4) * 4 + (j & 3);
        WfF[e] = f2bf((g < GTOT && i < L2D) ? Wf[g * L2D + i] : 0.0f);
    }
}

__global__ __launch_bounds__(256, 4)
void stp_mfma6_kernel(const float* __restrict__ inp,
                      const short* __restrict__ WtF,
                      const short* __restrict__ WfF,
                      float* __restrict__ out)
{
    const int tid  = threadIdx.x;
    const int lane = tid & 63;
    const int wave = tid >> 6;
    const int lm   = lane & 15;
    const int quad = lane >> 4;

    const int task = blockIdx.x * 4 + wave;   // 16384 tasks = (n, c-quarter)
    const int n    = task >> 2;
    const int q    = task & 3;

    const float* __restrict__ Xn = inp + (size_t)n * (L2D * CCH);

    // ---- X B-fragments straight from global: B[k=i][n=c] ----
    // lane holds c = q*32 + t*16 + lm ; i = kcx*32 + quad*8 + j
    bf16x8 Bx[2][2];
    #pragma unroll
    for (int t = 0; t < 2; ++t) {
        const int c = q * 32 + t * 16 + lm;
        #pragma unroll
        for (int kcx = 0; kcx < 2; ++kcx) {
            union { bf16x8 v; unsigned u[4]; } b;
            #pragma unroll
            for (int p = 0; p < 4; ++p) {
                const int i0 = kcx * 32 + quad * 8 + 2 * p;
                float v0 = (i0     < L2D) ? Xn[(i0    ) * CCH + c] : 0.0f;
                float v1 = (i0 + 1 < L2D) ? Xn[(i0 + 1) * CCH + c] : 0.0f;
                b.u[p] = cvtpk(v0, v1);
            }
            Bx[t][kcx] = b.v;
        }
    }

    f32x4 acc2[4][2];
    #pragma unroll
    for (int it = 0; it < 4; ++it)
        #pragma unroll
        for (int t = 0; t < 2; ++t)
            acc2[it][t] = (f32x4){0.0f, 0.0f, 0.0f, 0.0f};

    #pragma unroll 1
    for (int kc2 = 0; kc2 < KC2; ++kc2) {
        // W fragments for this g-chunk (16B coalesced, L1/L2-resident)
        bf16x8 Wtf[2][2];
        #pragma unroll
        for (int tt = 0; tt < 2; ++tt)
            #pragma unroll
            for (int kcx = 0; kcx < 2; ++kcx)
                Wtf[tt][kcx] = *(const bf16x8*)&WtF[(((2 * kc2 + tt) * 2 + kcx) * 64 + lane) * 8];
        bf16x8 Wff[4];
        #pragma unroll
        for (int it = 0; it < 4; ++it)
            Wff[it] = *(const bf16x8*)&WfF[((it * KC2 + kc2) * 64 + lane) * 8];

        #pragma unroll
        for (int t = 0; t < 2; ++t) {
            // stage 1: two 16-row g-tiles -> C-layout regs = B-frag halves
            union { bf16x8 v; unsigned u[4]; } bg;
            #pragma unroll
            for (int tt = 0; tt < 2; ++tt) {
                f32x4 g = (f32x4){0.0f, 0.0f, 0.0f, 0.0f};
                g = __builtin_amdgcn_mfma_f32_16x16x32_bf16(Wtf[tt][0], Bx[t][0], g, 0, 0, 0);
                g = __builtin_amdgcn_mfma_f32_16x16x32_bf16(Wtf[tt][1], Bx[t][1], g, 0, 0, 0);
                bg.u[tt * 2 + 0] = cvtpk(g[0] * g[0], g[1] * g[1]);
                bg.u[tt * 2 + 1] = cvtpk(g[2] * g[2], g[3] * g[3]);
            }
            // stage 2: accumulate out[i, c] over this g-chunk
            #pragma unroll
            for (int it = 0; it < 4; ++it)
                acc2[it][t] = __builtin_amdgcn_mfma_f32_16x16x32_bf16(Wff[it], bg.v, acc2[it][t], 0, 0, 0);
        }
    }

    // ---- store: C/D layout col=c=lm, row=i=it*16+quad*4+r ----
    float* __restrict__ On = out + (size_t)n * (L2D * CCH);
    #pragma unroll
    for (int it = 0; it < 4; ++it) {
        #pragma unroll
        for (int t = 0; t < 2; ++t) {
            const int c = q * 32 + t * 16 + lm;
            #pragma unroll
            for (int r = 0; r < 4; ++r) {
                const int i = it * 16 + quad * 4 + r;
                if (i < L2D) On[i * CCH + c] = acc2[it][t][r];
            }
        }
    }
}

extern "C" void kernel_launch(void* const* d_in, const int* in_sizes, int n_in,
                              void* d_out, int out_size, void* d_ws, size_t ws_size,
                              hipStream_t stream) {
    const float* inp = (const float*)d_in[0];   // (4096, 49, 128) fp32
    const float* Wt  = (const float*)d_in[1];   // (18*18, 49) fp32
    const float* Wf  = (const float*)d_in[2];   // (18*18, 49) fp32
    float* out = (float*)d_out;                 // (4096, 49, 128) fp32

    short* WtF = (short*)d_ws;
    short* WfF = WtF + WT_SHORTS;               // total 90112 B of ws

    const int prep_threads = WT_SHORTS + WF_SHORTS;   // 45056
    prep_w_kernel<<<(prep_threads + 255) / 256, 256, 0, stream>>>(Wt, Wf, WtF, WfF);
    stp_mfma6_kernel<<<4096, 256, 0, stream>>>(inp, WtF, WfF, out);
}

// Round 5
// 210.626 us; speedup vs baseline: 1.0978x; 1.0978x over previous
//
#include <hip/hip_runtime.h>

// SelfTensorProductS2Grid via bf16 MFMA, v7: both stages on 32x32x16.
//   grid[g,c] = sum_i Wt[g,i] X[i,c];  out[i,c] = sum_g Wf[g,i] grid[g,c]^2
// v2..v6 ledger: W-latency removal (v5) null; occupancy 1.8x (v6) regressed
// (VMEM issue doubled). Invariant ~92 us with MFMA pipe 23 us + VALU 29 us
// imperfectly overlapped -> remaining time attributed to per-instruction
// issue slots + MFMA->VALU hazard boundaries. v7 halves both: 176 instead of
// 352 MFMA/wave (32x32x16 = 2x FLOP/instr), 44 instead of 88 stage1->square
// hazard events, pipe 23 -> 19 us.
//
// g-relabel for 32x32: stage-1 C/D (col=lane&31, row=(reg&3)+8(reg>>2)+
// 4(lane>>5)) must BE stage-2's B operand (k=(lane>>5)*8+j per K=16 chunk).
// Assign tile-row m the in-chunk g:  gwc(m)=((m>>3)&1)*16+((m>>2)&1)*8+
// (m>>4)*4+(m&3)  (bit permutation, bijective). Then C/D regs {0-3,8-11}
// are exactly B-chunk cc=0 (j=0..7), regs {4-7,12-15} are cc=1, same lane.
// Stage-2 WfF uses identity g = kc2*32 + cc*16 + H*8 + j.

#define NN    4096
#define L2D   49
#define CCH   128
#define GTOT  324
#define KC2   11              // g-chunks of 32 (11*32 = 352, pad from 324)

typedef __attribute__((ext_vector_type(8)))  short bf16x8;
typedef __attribute__((ext_vector_type(16))) float f32x16;

#define WT_SHORTS (KC2 * 4 * 64 * 8)      // [kc2][ki][lane][j] = 22528
#define WF_SHORTS (2 * KC2 * 2 * 64 * 8)  // [it][kc2][cc][lane][j] = 22528

__device__ __forceinline__ short f2bf(float f) {
    union { float f; unsigned u; } x; x.f = f;
    return (short)((x.u + 0x7fffu + ((x.u >> 16) & 1u)) >> 16);   // RNE
}

// pack two f32 -> two bf16 (RNE) in one VALU op
__device__ __forceinline__ unsigned cvtpk(float lo, float hi) {
    unsigned r;
    asm("v_cvt_pk_bf16_f32 %0, %1, %2" : "=v"(r) : "v"(lo), "v"(hi));
    return r;
}

// WtF[kc2][ki][lane][j]: A[m=lane&31][k=i=ki*16+(lane>>5)*8+j], where the
//   physical g of tile-row m is kc2*32 + gwc(m).
// WfF[it][kc2][cc][lane][j]: A[m=i=it*32+(lane&31)][k: g=kc2*32+cc*16+
//   (lane>>5)*8+j]  (identity relabel on stage-2 side).
__global__ void prep_w_kernel(const float* __restrict__ Wt,
                              const float* __restrict__ Wf,
                              short* __restrict__ WtF,
                              short* __restrict__ WfF)
{
    int idx = blockIdx.x * 256 + threadIdx.x;
    if (idx < WT_SHORTS) {
        int j = idx & 7, lane = (idx >> 3) & 63, ki = (idx >> 9) & 3, kc2 = idx >> 11;
        int m = lane & 31, H = lane >> 5;
        int gwc = ((m >> 3) & 1) * 16 + ((m >> 2) & 1) * 8 + (m >> 4) * 4 + (m & 3);
        int g = kc2 * 32 + gwc;
        int i = ki * 16 + H * 8 + j;
        WtF[idx] = f2bf((g < GTOT && i < L2D) ? Wt[g * L2D + i] : 0.0f);
    } else if (idx < WT_SHORTS + WF_SHORTS) {
        int e = idx - WT_SHORTS;
        int j = e & 7, lane = (e >> 3) & 63, cc = (e >> 9) & 1;
        int u = e >> 10;                 // it*KC2 + kc2
        int kc2 = u % KC2, it = u / KC2;
        int m = lane & 31, H = lane >> 5;
        int i = it * 32 + m;
        int g = kc2 * 32 + cc * 16 + H * 8 + j;
        WfF[e] = f2bf((g < GTOT && i < L2D) ? Wf[g * L2D + i] : 0.0f);
    }
}

__global__ __launch_bounds__(256, 3)
void stp_mfma7_kernel(const float* __restrict__ inp,
                      const short* __restrict__ WtF,
                      const short* __restrict__ WfF,
                      float* __restrict__ out)
{
    const int tid  = threadIdx.x;
    const int lane = tid & 63;
    const int wave = tid >> 6;
    const int m    = lane & 31;       // col index within 32-tile
    const int H    = lane >> 5;       // k-half

    const int task = blockIdx.x * 4 + wave;   // 8192 tasks = (n, c-half)
    const int n    = task >> 1;
    const int h    = task & 1;

    const float* __restrict__ Xn = inp + (size_t)n * (L2D * CCH);

    // ---- X B-fragments from global: B[k=i][n=c], i = ki*16 + H*8 + j ----
    bf16x8 Bx[2][4];
    #pragma unroll
    for (int cq = 0; cq < 2; ++cq) {
        const int c = h * 64 + cq * 32 + m;
        #pragma unroll
        for (int ki = 0; ki < 4; ++ki) {
            union { bf16x8 v; unsigned u[4]; } b;
            #pragma unroll
            for (int p = 0; p < 4; ++p) {
                const int i0 = ki * 16 + H * 8 + 2 * p;
                float v0 = (i0     < L2D) ? Xn[(i0    ) * CCH + c] : 0.0f;
                float v1 = (i0 + 1 < L2D) ? Xn[(i0 + 1) * CCH + c] : 0.0f;
                b.u[p] = cvtpk(v0, v1);
            }
            Bx[cq][ki] = b.v;
        }
    }

    f32x16 acc2[2][2];   // [it][cq]
    #pragma unroll
    for (int it = 0; it < 2; ++it)
        #pragma unroll
        for (int cq = 0; cq < 2; ++cq)
            acc2[it][cq] = (f32x16)(0.0f);

    #pragma unroll 1
    for (int kc2 = 0; kc2 < KC2; ++kc2) {
        // W fragments for this g-chunk (16B coalesced, L1/L2-resident)
        bf16x8 Wtf[4];
        #pragma unroll
        for (int ki = 0; ki < 4; ++ki)
            Wtf[ki] = *(const bf16x8*)&WtF[((kc2 * 4 + ki) * 64 + lane) * 8];
        bf16x8 Wff[2][2];
        #pragma unroll
        for (int it = 0; it < 2; ++it)
            #pragma unroll
            for (int cc = 0; cc < 2; ++cc)
                Wff[it][cc] = *(const bf16x8*)&WfF[(((it * KC2 + kc2) * 2 + cc) * 64 + lane) * 8];

        #pragma unroll
        for (int cq = 0; cq < 2; ++cq) {
            // stage 1: one 32g x 32c tile, K = 64 (i padded 49->64)
            f32x16 g = (f32x16)(0.0f);
            #pragma unroll
            for (int ki = 0; ki < 4; ++ki)
                g = __builtin_amdgcn_mfma_f32_32x32x16_bf16(Wtf[ki], Bx[cq][ki], g, 0, 0, 0);

            // square + pack: C/D regs {0-3,8-11} -> B chunk cc=0 (j=0..7),
            //                regs {4-7,12-15} -> cc=1
            union { bf16x8 v; unsigned u[4]; } bg0, bg1;
            bg0.u[0] = cvtpk(g[0] * g[0],   g[1] * g[1]);
            bg0.u[1] = cvtpk(g[2] * g[2],   g[3] * g[3]);
            bg0.u[2] = cvtpk(g[8] * g[8],   g[9] * g[9]);
            bg0.u[3] = cvtpk(g[10] * g[10], g[11] * g[11]);
            bg1.u[0] = cvtpk(g[4] * g[4],   g[5] * g[5]);
            bg1.u[1] = cvtpk(g[6] * g[6],   g[7] * g[7]);
            bg1.u[2] = cvtpk(g[12] * g[12], g[13] * g[13]);
            bg1.u[3] = cvtpk(g[14] * g[14], g[15] * g[15]);

            // stage 2: out[i, c] += Wf[:, g-chunk] * grid^2
            #pragma unroll
            for (int it = 0; it < 2; ++it) {
                acc2[it][cq] = __builtin_amdgcn_mfma_f32_32x32x16_bf16(Wff[it][0], bg0.v, acc2[it][cq], 0, 0, 0);
                acc2[it][cq] = __builtin_amdgcn_mfma_f32_32x32x16_bf16(Wff[it][1], bg1.v, acc2[it][cq], 0, 0, 0);
            }
        }
    }

    // ---- store: C/D col=c, row i = it*32 + (r&3) + 8*(r>>2) + 4*H ----
    float* __restrict__ On = out + (size_t)n * (L2D * CCH);
    #pragma unroll
    for (int it = 0; it < 2; ++it) {
        #pragma unroll
        for (int cq = 0; cq < 2; ++cq) {
            const int c = h * 64 + cq * 32 + m;
            #pragma unroll
            for (int r = 0; r < 16; ++r) {
                const int i = it * 32 + (r & 3) + 8 * (r >> 2) + 4 * H;
                if (i < L2D) On[i * CCH + c] = acc2[it][cq][r];
            }
        }
    }
}

extern "C" void kernel_launch(void* const* d_in, const int* in_sizes, int n_in,
                              void* d_out, int out_size, void* d_ws, size_t ws_size,
                              hipStream_t stream) {
    const float* inp = (const float*)d_in[0];   // (4096, 49, 128) fp32
    const float* Wt  = (const float*)d_in[1];   // (18*18, 49) fp32
    const float* Wf  = (const float*)d_in[2];   // (18*18, 49) fp32
    float* out = (float*)d_out;                 // (4096, 49, 128) fp32

    short* WtF = (short*)d_ws;
    short* WfF = WtF + WT_SHORTS;               // total 90112 B of ws

    const int prep_threads = WT_SHORTS + WF_SHORTS;   // 45056
    prep_w_kernel<<<(prep_threads + 255) / 256, 256, 0, stream>>>(Wt, Wf, WtF, WfF);
    stp_mfma7_kernel<<<2048, 256, 0, stream>>>(inp, WtF, WfF, out);
}